// Round 3
// baseline (653.223 us; speedup 1.0000x reference)
//
#include <hip/hip_runtime.h>
#include <hip/hip_bf16.h>
#include <hip/hip_fp16.h>

// Problem constants (fixed by the reference)
#define N_GENES_MAX 5000
#define N_ELEM_MAX  4000000
#define PARAMS_PER_GENE 445

// R12: counting-sort elements by gene, then fused 3-stage eval in sorted
// order. Rationale (R11 post-mortem): scattered table probes cost ~1 L2
// lane-request each when tables are L2-resident (R9: 57us evalB) and a 64B
// L3 line when not (R11: 495MB FETCH, 161us). Sorting makes all lanes of a
// wave probe the SAME gene's 1.8KB table -> requests coalesce to a few
// lines, served from L1/broadcast; the L2 scattered-request floor vanishes.
// Also fuses all 3 stages (midstate gone; lad stays f32 end-to-end).
//
// Tables: proven R9 8B/knot format {loc f32, (h f16 <<16) | (cdf-loc) f16},
// concatenated per gene: 128+64+32 = 224 knots = 1792B/gene.
__device__ uint2 g_tab[(size_t)N_GENES_MAX * 224];
// Sorted records: {x u16 | gene u16, orig u32} — 8B/elem.
__device__ uint2 g_srec[N_ELEM_MAX];
__device__ unsigned g_hist[N_GENES_MAX];
__device__ unsigned g_cursor[N_GENES_MAX];

static __device__ __forceinline__ unsigned f2h(float f) {
    union { __half h; unsigned short u; } c;
    c.h = __float2half_rn(f);
    return (unsigned)c.u;
}
static __device__ __forceinline__ float h2f(unsigned u) {
    union { unsigned short u; __half h; } c;
    c.u = (unsigned short)u;
    return __half2float(c.h);
}

// ---- wave-level primitives (64 lanes) ----
static __device__ __forceinline__ float wscan_incl(float v) {
    const int lane = threadIdx.x & 63;
    #pragma unroll
    for (int off = 1; off < 64; off <<= 1) {
        float u = __shfl_up(v, off, 64);
        if (lane >= off) v += u;
    }
    return v;
}
static __device__ __forceinline__ int wscan_incl_i(int v) {
    const int lane = threadIdx.x & 63;
    #pragma unroll
    for (int off = 1; off < 64; off <<= 1) {
        int u = __shfl_up(v, off, 64);
        if (lane >= off) v += u;
    }
    return v;
}
static __device__ __forceinline__ float wmax64(float v) {
    #pragma unroll
    for (int off = 32; off > 0; off >>= 1) v = fmaxf(v, __shfl_xor(v, off, 64));
    return v;
}
static __device__ __forceinline__ float wsum64(float v) {
    #pragma unroll
    for (int off = 32; off > 0; off >>= 1) v += __shfl_xor(v, off, 64);
    return v;
}

// ---------------------------------------------------------------------------
// Kernel 1: build per-(gene,stage) knots into concatenated g_tab.
// grid=(G,3), block=128. (R8-verified scan logic; R9 8B knot format.)
// Also zeroes g_hist (one lane per gene) for the downstream histogram.
// ---------------------------------------------------------------------------
__global__ void build_knots(const float* __restrict__ params) {
    const int g = blockIdx.x;
    const int t = blockIdx.y;
    const int ns[3]   = {128, 64, 32};
    const int poff[3] = {0, 255, 382};
    const int koff[3] = {0, 128, 192};

    if (t == 0 && threadIdx.x == 0) g_hist[g] = 0;

    const int n = ns[t];
    const int m = n - 1;
    const float* ph = params + (size_t)g * PARAMS_PER_GENE + poff[t];
    const float* pw = ph + n;

    __shared__ float s2[2];
    __shared__ float s_scan[128];
    __shared__ float s_h[129];
    __shared__ float s_loc[128];
    __shared__ float s_cdf[128];

    const int tid  = threadIdx.x;
    const int lane = tid & 63;
    const int wv   = tid >> 6;

    const float uw = (tid < m) ? pw[tid] : -1e30f;
    float vmax = wmax64(uw);
    if (lane == 0) s2[wv] = vmax;
    __syncthreads();
    const float mx = fmaxf(s2[0], s2[1]);
    __syncthreads();

    const float e = (tid < m) ? __expf(uw - mx) : 0.0f;

    float sc = wscan_incl(e);
    if (lane == 63) s2[wv] = sc;
    __syncthreads();
    if (wv == 1) sc += s2[0];
    s_scan[tid] = sc;
    __syncthreads();

    const float S = s_scan[m - 1];
    const float invS = 1.0f / S;
    if (tid == 0) s_loc[0] = 0.0f;
    if (tid < m) s_loc[tid + 1] = (tid == m - 1) ? 1.0f : s_scan[tid] * invS;
    const float w_i = e * invS;

    const float eh = (tid < n) ? __expf(ph[tid]) : 0.0f;
    s_h[tid] = eh;
    if (tid == 0) s_h[128] = 0.0f;
    __syncthreads();

    const float term = (tid < m) ? 0.5f * (s_h[tid] + s_h[tid + 1]) * w_i : 0.0f;
    float ts = wsum64(term);
    if (lane == 0) s2[wv] = ts;
    __syncthreads();
    const float area = s2[0] + s2[1];
    __syncthreads();

    const float ia = 1.0f / area;
    const float hgt = eh * ia;

    float c = wscan_incl(term * ia);
    if (lane == 63) s2[wv] = c;
    __syncthreads();
    if (wv == 1) c += s2[0];
    s_scan[tid] = c;
    __syncthreads();

    if (tid == 0) s_cdf[0] = 0.0f;
    if (tid < m) s_cdf[tid + 1] = (tid == m - 1) ? 1.0f : s_scan[tid];
    __syncthreads();

    if (tid < n) {
        const float loc = s_loc[tid];
        uint2 kt;
        kt.x = __float_as_uint(loc);
        kt.y = (f2h(hgt) << 16) | f2h(s_cdf[tid] - loc);
        g_tab[(size_t)g * 224 + koff[t] + tid] = kt;
    }
}

typedef float fvec4 __attribute__((ext_vector_type(4)));
typedef int   ivec4 __attribute__((ext_vector_type(4)));
typedef unsigned uvec4 __attribute__((ext_vector_type(4)));

// ---------------------------------------------------------------------------
// Kernel 2: gene histogram. 4 elems/thread.
// ---------------------------------------------------------------------------
__global__ void hist_kernel(const int* __restrict__ gix, int N) {
    const int i4 = (blockIdx.x * blockDim.x + threadIdx.x) * 4;
    if (i4 + 3 < N) {
        const ivec4 gv = *(const ivec4*)(gix + i4);
        atomicAdd(&g_hist[gv.x], 1u);
        atomicAdd(&g_hist[gv.y], 1u);
        atomicAdd(&g_hist[gv.z], 1u);
        atomicAdd(&g_hist[gv.w], 1u);
    } else {
        for (int j = i4; j < N; ++j) atomicAdd(&g_hist[gix[j]], 1u);
    }
}

// ---------------------------------------------------------------------------
// Kernel 3: exclusive scan of g_hist -> g_cursor. One block, 1024 threads,
// 5 entries/thread (covers G <= 5120).
// ---------------------------------------------------------------------------
__global__ void scan_kernel(int G) {
    const int t = threadIdx.x;
    const int lane = t & 63;
    const int wv = t >> 6;
    __shared__ int ws[16];

    int c[5];
    int s = 0;
    #pragma unroll
    for (int j = 0; j < 5; ++j) {
        const int idx = t * 5 + j;
        const int v = (idx < G) ? (int)g_hist[idx] : 0;
        c[j] = s;
        s += v;
    }
    int sc = wscan_incl_i(s);
    if (lane == 63) ws[wv] = sc;
    __syncthreads();
    int wbase = 0;
    for (int k = 0; k < wv; ++k) wbase += ws[k];
    const int excl = wbase + sc - s;
    #pragma unroll
    for (int j = 0; j < 5; ++j) {
        const int idx = t * 5 + j;
        if (idx < G) g_cursor[idx] = (unsigned)(excl + c[j]);
    }
}

// ---------------------------------------------------------------------------
// Kernel 4: scatter into gene-sorted order. Record: {x u16 | gene u16, orig}.
// x-quantization err 2^-17 ~ 7.6e-6 (negligible vs f16 heights already used).
// ---------------------------------------------------------------------------
__global__ void scatter_kernel(const float* __restrict__ x_in,
                               const int* __restrict__ gix, int N) {
    const int i4 = (blockIdx.x * blockDim.x + threadIdx.x) * 4;
    if (i4 + 3 < N) {
        const fvec4 xv = __builtin_nontemporal_load((const fvec4*)(x_in + i4));
        const ivec4 gv = __builtin_nontemporal_load((const ivec4*)(gix + i4));
        #pragma unroll
        for (int k = 0; k < 4; ++k) {
            const int g = (k == 0) ? gv.x : (k == 1) ? gv.y : (k == 2) ? gv.z : gv.w;
            const float xf = (k == 0) ? xv.x : (k == 1) ? xv.y : (k == 2) ? xv.z : xv.w;
            const unsigned pos = atomicAdd(&g_cursor[g], 1u);
            const unsigned xq = __float2uint_rn(fminf(fmaxf(xf, 0.0f), 1.0f) * 65535.0f);
            uint2 r;
            r.x = xq | ((unsigned)g << 16);
            r.y = (unsigned)(i4 + k);
            g_srec[pos] = r;
        }
    } else {
        for (int j = i4; j < N; ++j) {
            const int g = gix[j];
            const unsigned pos = atomicAdd(&g_cursor[g], 1u);
            const unsigned xq = __float2uint_rn(fminf(fmaxf(x_in[j], 0.0f), 1.0f) * 65535.0f);
            uint2 r;
            r.x = xq | ((unsigned)g << 16);
            r.y = (unsigned)j;
            g_srec[pos] = r;
        }
    }
}

// ---------------------------------------------------------------------------
// Stage evaluation from packed 8B knots (R9-proven logic).
// ---------------------------------------------------------------------------
template <int K>
static __device__ __forceinline__ void stage(const uint2* __restrict__ kn,
                                             float& x, float& lad) {
    int b = (int)(x * (float)(K - 1));
    b = (b < 0) ? 0 : ((b > K - 2) ? K - 2 : b);
    uint2 k0 = kn[b];
    uint2 k1 = kn[b + 1];
    float l0 = __uint_as_float(k0.x);
    float l1 = __uint_as_float(k1.x);
    while (b > 0 && l0 > x) {
        --b;
        k1 = k0; l1 = l0;
        k0 = kn[b]; l0 = __uint_as_float(k0.x);
    }
    while (b < K - 2 && l1 <= x) {
        ++b;
        k0 = k1; l0 = l1;
        k1 = kn[b + 1]; l1 = __uint_as_float(k1.x);
    }
    const float lh = h2f(k0.y >> 16);
    const float rh = h2f(k1.y >> 16);
    const float lc = l0 + h2f(k0.y & 0xffffu);
    const float w  = l1 - l0;
    const float alpha = (x - l0) / w;
    float o = (0.5f * (rh - lh) * w) * alpha * alpha + (lh * w) * alpha + lc;
    o = fminf(fmaxf(o, 0.0f), 1.0f);
    lad += __logf(alpha * (rh - lh) + lh);
    x = o;
}

// ---------------------------------------------------------------------------
// Kernel 5: fused 3-stage eval in gene-sorted order. 2 elems/thread.
// XCD-chunked block swizzle: each XCD's L2 caches only its ~1/8 gene slice.
// ---------------------------------------------------------------------------
__global__ void eval_kernel(float* __restrict__ out, int N, int nwg) {
    const int o = blockIdx.x;
    const int xcd = o & 7;
    const int pos = o >> 3;
    const int q = nwg >> 3;
    const int r = nwg & 7;
    const int bid = (xcd < r ? xcd * (q + 1) : r * (q + 1) + (xcd - r) * q) + pos;

    const int i = bid * blockDim.x + threadIdx.x;
    const long i2 = (long)i * 2;
    if (i2 + 1 < N) {
        const uvec4 rr = __builtin_nontemporal_load((const uvec4*)(g_srec + i2));
        float x0 = (float)(rr.x & 0xffffu) * (1.0f / 65535.0f);
        float x1 = (float)(rr.z & 0xffffu) * (1.0f / 65535.0f);
        const int g0 = (int)(rr.x >> 16);
        const int g1 = (int)(rr.z >> 16);
        float l0 = 0.0f, l1 = 0.0f;
        const uint2* t0 = g_tab + (size_t)g0 * 224;
        const uint2* t1 = g_tab + (size_t)g1 * 224;
        stage<128>(t0, x0, l0);
        stage<128>(t1, x1, l1);
        stage<64>(t0 + 128, x0, l0);
        stage<64>(t1 + 128, x1, l1);
        stage<32>(t0 + 192, x0, l0);
        stage<32>(t1 + 192, x1, l1);
        // scattered 4B stores: NORMAL stores (L2 write-combines lines).
        out[rr.y] = x0;
        out[(size_t)N + rr.y] = l0;
        out[rr.w] = x1;
        out[(size_t)N + rr.w] = l1;
    } else if (i2 < N) {
        const uint2 rr = g_srec[i2];
        float x0 = (float)(rr.x & 0xffffu) * (1.0f / 65535.0f);
        const int g0 = (int)(rr.x >> 16);
        float l0 = 0.0f;
        const uint2* t0 = g_tab + (size_t)g0 * 224;
        stage<128>(t0, x0, l0);
        stage<64>(t0 + 128, x0, l0);
        stage<32>(t0 + 192, x0, l0);
        out[rr.y] = x0;
        out[(size_t)N + rr.y] = l0;
    }
}

// ---------------------------------------------------------------------------
extern "C" void kernel_launch(void* const* d_in, const int* in_sizes, int n_in,
                              void* d_out, int out_size, void* d_ws, size_t ws_size,
                              hipStream_t stream) {
    const float* x      = (const float*)d_in[0];
    const int*   gix    = (const int*)d_in[1];
    const float* params = (const float*)d_in[2];
    float* out = (float*)d_out;

    const int N = in_sizes[0];
    const int G = in_sizes[2] / PARAMS_PER_GENE;

    // 1) tables (+ hist zero)
    build_knots<<<dim3(G, 3), 128, 0, stream>>>(params);

    const int block = 256;
    // 2) histogram
    const int n4 = (N + 3) / 4;
    hist_kernel<<<(n4 + block - 1) / block, block, 0, stream>>>(gix, N);
    // 3) exclusive scan -> cursors
    scan_kernel<<<1, 1024, 0, stream>>>(G);
    // 4) scatter into sorted order
    scatter_kernel<<<(n4 + block - 1) / block, block, 0, stream>>>(x, gix, N);
    // 5) fused eval
    const int nh = (N + 1) / 2;
    const int nwg = (nh + block - 1) / block;
    eval_kernel<<<nwg, block, 0, stream>>>(out, N, nwg);
}